// Round 13
// baseline (388.106 us; speedup 1.0000x reference)
//
#include <hip/hip_runtime.h>
#include <math.h>

// OverlapTripletLoss: C=64 classes, K=64, ALPHA=1, N=131072, D=256, fp32.
// Two pipelines, selected by ws_size (pure function of a constant -> capture-safe):
//  BIG (needs ~169 MB): prep/count/scan/fill -> gatherK (wave-per-row bf16
//    hi/lo gather, group-sorted) -> gemmK (streaming MFMA, mu in LDS) ->
//    selK -> lossK.
//  SMALL (needs ~34 MB): round-7 fused distK (mu+x staged in LDS per-chunk,
//    measured passing) -> selK -> lossK.

#define DDIM 256
#define CC 64
#define KSEL 64
#define MS 264     // mu LDS stride (shorts) in gemmK: 528 B, b128-aligned
#define SELN 2048
#define TPTSF 256  // points per wg in fused distK (fallback)
#define XSF 48     // fused distK LDS row stride (shorts)

typedef short s4v __attribute__((ext_vector_type(4)));
typedef short s8v __attribute__((ext_vector_type(8)));
typedef float f4v __attribute__((ext_vector_type(4)));

__device__ __forceinline__ void cvt_split(float f, short& h, short& l) {
  const unsigned int u = __float_as_uint(f);
  const unsigned int hb = (u + 0x7FFFu + ((u >> 16) & 1u)) >> 16;   // RNE bf16
  h = (short)hb;
  const float rem = f - __uint_as_float(hb << 16);
  const unsigned int ur = __float_as_uint(rem);
  l = (short)((ur + 0x7FFFu + ((ur >> 16) & 1u)) >> 16);
}

// prepK: wg0 zeroes cnt/cnt2; 16 wgs convert mu (64x256) to bf16 hi/lo + norms.
__global__ __launch_bounds__(256) void prepK(const float* __restrict__ mu, short* __restrict__ mhG,
                                             short* __restrict__ mlG, float* __restrict__ mn2G,
                                             int* __restrict__ cnts) {
  const int b = blockIdx.x, t = threadIdx.x;
  if (b == 0 && t < 128) cnts[t] = 0;
  const int row = b * 4 + (t >> 6), l = t & 63;
  const float4 v = *reinterpret_cast<const float4*>(mu + (size_t)row * DDIM + l * 4);
  const float vs[4] = {v.x, v.y, v.z, v.w};
  s4v hv, lv;
  float s2 = 0.f;
  #pragma unroll
  for (int j = 0; j < 4; ++j) {
    short hj, lj; cvt_split(vs[j], hj, lj);
    hv[j] = hj; lv[j] = lj;
    s2 = fmaf(vs[j], vs[j], s2);
  }
  *reinterpret_cast<s4v*>(&mhG[(size_t)row * DDIM + l * 4]) = hv;
  *reinterpret_cast<s4v*>(&mlG[(size_t)row * DDIM + l * 4]) = lv;
  #pragma unroll
  for (int off = 32; off > 0; off >>= 1) s2 += __shfl_xor(s2, off, 64);
  if (l == 0) mn2G[row] = s2;
}

__global__ __launch_bounds__(256) void countK(const int* __restrict__ y, int* cnt, int N) {
  int i = blockIdx.x * 256 + threadIdx.x;
  if (i < N) atomicAdd(&cnt[y[3 * i + 2] & (CC - 1)], 1);
}

__global__ void scanK(const int* __restrict__ cnt, int* base) {
  if (threadIdx.x == 0) {
    int s = 0;
    for (int i = 0; i < CC; ++i) { base[i] = s; s += cnt[i]; }
  }
}

__global__ __launch_bounds__(256) void fillK(const int* __restrict__ y, const int* __restrict__ base,
                                             int* cnt2, int* idxs, int N) {
  int i = blockIdx.x * 256 + threadIdx.x;
  if (i < N) {
    int m = y[3 * i + 2] & (CC - 1);
    int r = atomicAdd(&cnt2[m], 1);      // order within group is irrelevant
    idxs[base[m] + r] = i;
  }
}

// ---------------- BIG path: gatherK + gemmK ----------------

// gatherK: one wave per output slot. 64 lanes x float4 = whole 1-KB row in ONE
// instruction; cvt; two coalesced 512-B stores; wave-reduced norm. No LDS/barriers.
__global__ __launch_bounds__(256) void gatherK(const float* __restrict__ x, const int* __restrict__ idxs,
                                               short* __restrict__ xsh, short* __restrict__ xsl,
                                               float* __restrict__ xn2, int N) {
  const int slot = blockIdx.x * 4 + (threadIdx.x >> 6);
  const int l = threadIdx.x & 63;
  const int src = idxs[slot];            // wave-uniform -> broadcast
  const float4 v = *reinterpret_cast<const float4*>(x + (size_t)src * DDIM + l * 4);
  const float vs[4] = {v.x, v.y, v.z, v.w};
  s4v hv, lv;
  float s2 = 0.f;
  #pragma unroll
  for (int j = 0; j < 4; ++j) {
    short hj, lj; cvt_split(vs[j], hj, lj);
    hv[j] = hj; lv[j] = lj;
    s2 = fmaf(vs[j], vs[j], s2);
  }
  *reinterpret_cast<s4v*>(xsh + (size_t)slot * DDIM + l * 4) = hv;
  *reinterpret_cast<s4v*>(xsl + (size_t)slot * DDIM + l * 4) = lv;
  #pragma unroll
  for (int off = 32; off > 0; off >>= 1) s2 += __shfl_xor(s2, off, 64);
  if (l == 0) xn2[slot] = s2;
}

// gemmK: 256 pts/wg (wave w owns 64 pts = 4 n-tiles) x 64 centroids (4 m-tiles),
// K=256 in 8 chunks. A = mu hi/lo staged ONCE in LDS; B = group-sorted xs from
// global (each row exactly once, 64-B sectors, L3-hot), reg-double-buffered.
// Verified gfx950 16x16x32 mapping: a/b lane l -> (idx=l&15, k=(l>>4)*8+e);
// D lane l reg r -> (row=(l>>4)*4+r, col=l&15).
__global__ __launch_bounds__(256, 2) void gemmK(const short* __restrict__ xsh, const short* __restrict__ xsl,
                                                const short* __restrict__ mhG, const short* __restrict__ mlG,
                                                const float* __restrict__ mn2G, const float* __restrict__ xn2,
                                                float* __restrict__ Dg, int N) {
  __shared__ __align__(16) short mh[CC][MS];
  __shared__ __align__(16) short ml[CC][MS];
  const int t = threadIdx.x;
  const int w = t >> 6, l = t & 63;
  const int lr = l & 15, lk = l >> 4;

  #pragma unroll
  for (int j = 0; j < 8; ++j) {
    const int f = j * 2048 + t * 8;      // flat short index, covers 64*256
    const int row = f >> 8, col = f & 255;
    *reinterpret_cast<s8v*>(&mh[row][col]) = *reinterpret_cast<const s8v*>(mhG + f);
    *reinterpret_cast<s8v*>(&ml[row][col]) = *reinterpret_cast<const s8v*>(mlG + f);
  }
  __syncthreads();

  const int pbase = blockIdx.x * 256 + w * 64;

  s8v bhq[2][4], blq[2][4];
  #pragma unroll
  for (int nt = 0; nt < 4; ++nt) {
    const size_t ro = (size_t)(pbase + nt * 16 + lr) * DDIM + lk * 8;
    bhq[0][nt] = *reinterpret_cast<const s8v*>(xsh + ro);
    blq[0][nt] = *reinterpret_cast<const s8v*>(xsl + ro);
  }

  f4v acc[4][4];                         // [m-tile][n-tile]
  #pragma unroll
  for (int a = 0; a < 4; ++a)
    #pragma unroll
    for (int b = 0; b < 4; ++b) acc[a][b] = (f4v)0.f;

  #pragma unroll
  for (int ch = 0; ch < 8; ++ch) {
    const int cur = ch & 1, nxt = cur ^ 1;   // compile-time after unroll
    if (ch < 7) {                            // prefetch next B chunk
      #pragma unroll
      for (int nt = 0; nt < 4; ++nt) {
        const size_t ro = (size_t)(pbase + nt * 16 + lr) * DDIM + (ch + 1) * 32 + lk * 8;
        bhq[nxt][nt] = *reinterpret_cast<const s8v*>(xsh + ro);
        blq[nxt][nt] = *reinterpret_cast<const s8v*>(xsl + ro);
      }
    }
    s8v ah[4], al_[4];
    #pragma unroll
    for (int mt = 0; mt < 4; ++mt) {
      ah[mt]  = *reinterpret_cast<const s8v*>(&mh[mt * 16 + lr][ch * 32 + lk * 8]);
      al_[mt] = *reinterpret_cast<const s8v*>(&ml[mt * 16 + lr][ch * 32 + lk * 8]);
    }
    #pragma unroll
    for (int mt = 0; mt < 4; ++mt) {
      #pragma unroll
      for (int nt = 0; nt < 4; ++nt) {
        acc[mt][nt] = __builtin_amdgcn_mfma_f32_16x16x32_bf16(ah[mt],  bhq[cur][nt], acc[mt][nt], 0, 0, 0);
        acc[mt][nt] = __builtin_amdgcn_mfma_f32_16x16x32_bf16(ah[mt],  blq[cur][nt], acc[mt][nt], 0, 0, 0);
        acc[mt][nt] = __builtin_amdgcn_mfma_f32_16x16x32_bf16(al_[mt], bhq[cur][nt], acc[mt][nt], 0, 0, 0);
      }
    }
  }

  #pragma unroll
  for (int nt = 0; nt < 4; ++nt) {
    const int p = pbase + nt * 16 + lr;
    const float xn = xn2[p];
    #pragma unroll
    for (int mt = 0; mt < 4; ++mt) {
      #pragma unroll
      for (int r = 0; r < 4; ++r) {
        const int m = mt * 16 + lk * 4 + r;
        const float d2 = mn2G[m] + xn - 2.f * acc[mt][nt][r];
        Dg[(size_t)m * N + p] = sqrtf(fmaxf(d2, 0.f));
      }
    }
  }
}

// ---------------- SMALL path: round-7 fused distK (measured passing) ----------------

__global__ __launch_bounds__(256) void distKf(const float* __restrict__ x, const float* __restrict__ mu,
                                              const int* __restrict__ idxs, float* __restrict__ Dg, int N) {
  __shared__ __align__(16) short xh[TPTSF][XSF];
  __shared__ __align__(16) short xl[TPTSF][XSF];
  __shared__ __align__(16) short mh[CC][XSF];
  __shared__ __align__(16) short ml[CC][XSF];
  __shared__ int pid[TPTSF];
  __shared__ float xn2[TPTSF];
  __shared__ float mn2[CC];

  const int t = threadIdx.x;
  const int wgp0 = blockIdx.x * TPTSF;
  pid[t] = idxs[wgp0 + t];

  const int q = t & 7,  pr = t >> 3;
  const int q2 = t & 3, mm = t >> 2;
  const int w = t >> 6, l = t & 63;
  const int lr = l & 15, lk = l >> 4;

  f4v acc[4][4];
  #pragma unroll
  for (int a = 0; a < 4; ++a)
    #pragma unroll
    for (int b = 0; b < 4; ++b) acc[a][b] = (f4v)0.f;
  float xnacc[8] = {0.f, 0.f, 0.f, 0.f, 0.f, 0.f, 0.f, 0.f};
  float mnacc = 0.f;

  __syncthreads();
  int pidr[8];
  #pragma unroll
  for (int r = 0; r < 8; ++r) pidr[r] = pid[r * 32 + pr];

  for (int ch = 0; ch < 8; ++ch) {
    const int kb = ch * 32;
    if (ch) __syncthreads();
    #pragma unroll
    for (int r = 0; r < 8; ++r) {
      const float4 v = *reinterpret_cast<const float4*>(x + (size_t)pidr[r] * DDIM + kb + q * 4);
      const float vs[4] = {v.x, v.y, v.z, v.w};
      s4v hv, lv;
      float s2 = 0.f;
      #pragma unroll
      for (int j = 0; j < 4; ++j) {
        short hj, lj; cvt_split(vs[j], hj, lj);
        hv[j] = hj; lv[j] = lj;
        s2 = fmaf(vs[j], vs[j], s2);
      }
      xnacc[r] += s2;
      const int p = r * 32 + pr;
      *reinterpret_cast<s4v*>(&xh[p][q * 4]) = hv;
      *reinterpret_cast<s4v*>(&xl[p][q * 4]) = lv;
    }
    {
      const float* msrc = mu + (size_t)mm * DDIM + kb + q2 * 8;
      const float4 va = *reinterpret_cast<const float4*>(msrc);
      const float4 vb = *reinterpret_cast<const float4*>(msrc + 4);
      const float vs[8] = {va.x, va.y, va.z, va.w, vb.x, vb.y, vb.z, vb.w};
      s4v h0, h1, l0, l1;
      #pragma unroll
      for (int j = 0; j < 4; ++j) {
        short hj, lj; cvt_split(vs[j], hj, lj);
        h0[j] = hj; l0[j] = lj;
        mnacc = fmaf(vs[j], vs[j], mnacc);
      }
      #pragma unroll
      for (int j = 0; j < 4; ++j) {
        short hj, lj; cvt_split(vs[4 + j], hj, lj);
        h1[j] = hj; l1[j] = lj;
        mnacc = fmaf(vs[4 + j], vs[4 + j], mnacc);
      }
      *reinterpret_cast<s4v*>(&mh[mm][q2 * 8])     = h0;
      *reinterpret_cast<s4v*>(&mh[mm][q2 * 8 + 4]) = h1;
      *reinterpret_cast<s4v*>(&ml[mm][q2 * 8])     = l0;
      *reinterpret_cast<s4v*>(&ml[mm][q2 * 8 + 4]) = l1;
    }
    __syncthreads();
    s8v ah[4], al_[4];
    #pragma unroll
    for (int mt = 0; mt < 4; ++mt) {
      ah[mt]  = *reinterpret_cast<const s8v*>(&mh[mt * 16 + lr][lk * 8]);
      al_[mt] = *reinterpret_cast<const s8v*>(&ml[mt * 16 + lr][lk * 8]);
    }
    #pragma unroll
    for (int nt = 0; nt < 4; ++nt) {
      const int prow = w * 64 + nt * 16 + lr;
      const s8v bh = *reinterpret_cast<const s8v*>(&xh[prow][lk * 8]);
      const s8v bl = *reinterpret_cast<const s8v*>(&xl[prow][lk * 8]);
      #pragma unroll
      for (int mt = 0; mt < 4; ++mt) {
        acc[mt][nt] = __builtin_amdgcn_mfma_f32_16x16x32_bf16(ah[mt],  bh, acc[mt][nt], 0, 0, 0);
        acc[mt][nt] = __builtin_amdgcn_mfma_f32_16x16x32_bf16(ah[mt],  bl, acc[mt][nt], 0, 0, 0);
        acc[mt][nt] = __builtin_amdgcn_mfma_f32_16x16x32_bf16(al_[mt], bh, acc[mt][nt], 0, 0, 0);
      }
    }
  }
  #pragma unroll
  for (int r = 0; r < 8; ++r) {
    float s = xnacc[r];
    s += __shfl_xor(s, 1, 64); s += __shfl_xor(s, 2, 64); s += __shfl_xor(s, 4, 64);
    if (q == 0) xn2[r * 32 + pr] = s;
  }
  {
    float s = mnacc;
    s += __shfl_xor(s, 1, 64); s += __shfl_xor(s, 2, 64);
    if (q2 == 0) mn2[mm] = s;
  }
  __syncthreads();
  #pragma unroll
  for (int mt = 0; mt < 4; ++mt) {
    #pragma unroll
    for (int r = 0; r < 4; ++r) {
      const int m = mt * 16 + lk * 4 + r;
      const float mn = mn2[m];
      #pragma unroll
      for (int nt = 0; nt < 4; ++nt) {
        const int p = w * 64 + nt * 16 + lr;
        const float d2 = mn + xn2[p] - 2.f * acc[mt][nt][r];
        Dg[(size_t)m * N + wgp0 + p] = sqrtf(fmaxf(d2, 0.f));
      }
    }
  }
}

// ---------------- shared tail: selK + lossK ----------------

__global__ __launch_bounds__(128) void selK(const float* __restrict__ Dg, const int* __restrict__ cnt,
                                            const int* __restrict__ base, float* __restrict__ posM,
                                            float* __restrict__ neg, int N) {
  __shared__ __align__(16) unsigned int keys[SELN];
  __shared__ unsigned int sh_lo, sh_hi;
  __shared__ int sh_cnt[2];
  __shared__ float sh_sum[2];
  const int c = blockIdx.x, m = blockIdx.y;
  const int t = threadIdx.x;
  const int w = t >> 6, lane = t & 63;
  const bool diag = (c == m);
  int cm = cnt[m]; if (cm > SELN) cm = SELN;
  const int bm = base[m];
  const float* src = Dg + (size_t)c * N + bm;
  const int cm4 = (cm + 3) & ~3;

  unsigned int kmin = 0xFFFFFFFFu, kmax = 0u;
  for (int i = t; i < cm4; i += 128) {
    unsigned int key = 0xFFFFFFFFu;
    if (i < cm) {
      const unsigned int b = __float_as_uint(src[i]);
      key = diag ? ~b : b;
      kmin = min(kmin, key); kmax = max(kmax, key);
    }
    keys[i] = key;
  }
  #pragma unroll
  for (int off = 32; off > 0; off >>= 1) {
    kmin = min(kmin, (unsigned int)__shfl_xor((int)kmin, off, 64));
    kmax = max(kmax, (unsigned int)__shfl_xor((int)kmax, off, 64));
  }
  if (lane == 0) { sh_cnt[w] = (int)kmin; sh_sum[w] = __uint_as_float(kmax); }
  __syncthreads();
  if (t == 0) {
    sh_lo = min((unsigned int)sh_cnt[0], (unsigned int)sh_cnt[1]);
    sh_hi = max(__float_as_uint(sh_sum[0]), __float_as_uint(sh_sum[1]));
  }

  for (;;) {
    __syncthreads();
    const unsigned int lo = sh_lo, hi = sh_hi;
    if (lo >= hi) break;
    const unsigned int mid = lo + ((hi - lo) >> 1);
    int cl = 0;
    for (int i4 = t * 4; i4 < cm4; i4 += 512) {
      const uint4 kv = *reinterpret_cast<const uint4*>(&keys[i4]);
      cl += (int)(kv.x <= mid) + (int)(kv.y <= mid) + (int)(kv.z <= mid) + (int)(kv.w <= mid);
    }
    #pragma unroll
    for (int off = 32; off > 0; off >>= 1) cl += __shfl_xor(cl, off, 64);
    if (lane == 0) sh_cnt[w] = cl;
    __syncthreads();
    if (t == 0) {
      if (sh_cnt[0] + sh_cnt[1] >= KSEL) sh_hi = mid; else sh_lo = mid + 1;
    }
  }
  const unsigned int kth = sh_lo;

  int cl = 0; float sl = 0.f;
  for (int i4 = t * 4; i4 < cm4; i4 += 512) {
    const uint4 kv = *reinterpret_cast<const uint4*>(&keys[i4]);
    const unsigned int ks[4] = {kv.x, kv.y, kv.z, kv.w};
    #pragma unroll
    for (int j = 0; j < 4; ++j) {
      if (ks[j] < kth) { ++cl; sl += __uint_as_float(diag ? ~ks[j] : ks[j]); }
    }
  }
  #pragma unroll
  for (int off = 32; off > 0; off >>= 1) {
    cl += __shfl_xor(cl, off, 64);
    sl += __shfl_xor(sl, off, 64);
  }
  if (lane == 0) { sh_cnt[w] = cl; sh_sum[w] = sl; }
  __syncthreads();
  if (t == 0) {
    const int totc = sh_cnt[0] + sh_cnt[1];
    const float tots = sh_sum[0] + sh_sum[1];
    const float kval = __uint_as_float(diag ? ~kth : kth);
    const float mval = (tots + (float)(KSEL - totc) * kval) * (1.0f / KSEL);
    if (diag) posM[c] = mval; else neg[m * CC + c] = mval;
  }
}

__global__ __launch_bounds__(256) void lossK(const float* __restrict__ posM, const float* __restrict__ neg,
                                             float* __restrict__ out, int N) {
  __shared__ float red[256];
  const int t = threadIdx.x;
  float s = 0.f;
  for (int idx = t; idx < CC * CC; idx += 256) {
    const int m = idx >> 6, c = idx & 63;
    if (m != c) {
      const float h = 1.0f + posM[c] - neg[idx];
      s += fmaxf(h, 0.0f);
    }
  }
  red[t] = s;
  __syncthreads();
  for (int off = 128; off > 0; off >>= 1) {
    if (t < off) red[t] += red[t + off];
    __syncthreads();
  }
  if (t == 0) out[0] = red[0] / (float)N;
}

__global__ void wsFailK(float* out) {
  if (threadIdx.x == 0) out[0] = -1.0e30f;  // sentinel: workspace too small
}

extern "C" void kernel_launch(void* const* d_in, const int* in_sizes, int n_in,
                              void* d_out, int out_size, void* d_ws, size_t ws_size,
                              hipStream_t stream) {
  const float* x  = (const float*)d_in[0];
  const int*   y  = (const int*)d_in[1];
  const float* mu = (const float*)d_in[2];
  float* out = (float*)d_out;
  const int N = in_sizes[0] / DDIM;

  // Common small region:
  //   0: cnt[64], 256: cnt2[64], 512: base[64], 768: posM[64],
  //   1024: neg[4096] (16 KB), 17408: mn2G[64],
  //   20480: mhG (32 KB), 53248: mlG (32 KB), 131072: idxs[N] (512 KB)
  char* w = (char*)d_ws;
  int*   cnt  = (int*)(w);
  int*   cnt2 = (int*)(w + 256);
  int*   base = (int*)(w + 512);
  float* posM = (float*)(w + 768);
  float* neg  = (float*)(w + 1024);
  float* mn2G = (float*)(w + 17408);
  short* mhG  = (short*)(w + 20480);
  short* mlG  = (short*)(w + 53248);
  int*   idxs = (int*)(w + 131072);

  const size_t needBig   = (size_t)135397376 + (size_t)CC * (size_t)N * 4;  // ~169 MB
  const size_t needSmall = (size_t)655360    + (size_t)CC * (size_t)N * 4;  // ~34 MB

  if (ws_size >= needBig) {
    // BIG: 655360: xn2[N] (512 KB), 1179648: xsh (64 MB), 68288512: xsl (64 MB),
    //      135397376: Dg (32 MB)
    float* xn2 = (float*)(w + 655360);
    short* xsh = (short*)(w + 1179648);
    short* xsl = (short*)(w + 68288512);
    float* Dg  = (float*)(w + 135397376);
    hipLaunchKernelGGL(prepK, dim3(16), dim3(256), 0, stream, mu, mhG, mlG, mn2G, cnt);
    hipLaunchKernelGGL(countK, dim3((N + 255) / 256), dim3(256), 0, stream, y, cnt, N);
    hipLaunchKernelGGL(scanK, dim3(1), dim3(64), 0, stream, cnt, base);
    hipLaunchKernelGGL(fillK, dim3((N + 255) / 256), dim3(256), 0, stream, y, base, cnt2, idxs, N);
    hipLaunchKernelGGL(gatherK, dim3(N / 4), dim3(256), 0, stream, x, idxs, xsh, xsl, xn2, N);
    hipLaunchKernelGGL(gemmK, dim3(N / 256), dim3(256), 0, stream, xsh, xsl, mhG, mlG, mn2G, xn2, Dg, N);
    hipLaunchKernelGGL(selK, dim3(CC, CC), dim3(128), 0, stream, Dg, cnt, base, posM, neg, N);
    hipLaunchKernelGGL(lossK, dim3(1), dim3(256), 0, stream, posM, neg, out, N);
  } else if (ws_size >= needSmall) {
    // SMALL: 655360: Dg (32 MB). Fused distK (round-7 structure, measured).
    float* Dg = (float*)(w + 655360);
    hipLaunchKernelGGL(prepK, dim3(16), dim3(256), 0, stream, mu, mhG, mlG, mn2G, cnt);
    hipLaunchKernelGGL(countK, dim3((N + 255) / 256), dim3(256), 0, stream, y, cnt, N);
    hipLaunchKernelGGL(scanK, dim3(1), dim3(64), 0, stream, cnt, base);
    hipLaunchKernelGGL(fillK, dim3((N + 255) / 256), dim3(256), 0, stream, y, base, cnt2, idxs, N);
    hipLaunchKernelGGL(distKf, dim3(N / TPTSF), dim3(256), 0, stream, x, mu, idxs, Dg, N);
    hipLaunchKernelGGL(selK, dim3(CC, CC), dim3(128), 0, stream, Dg, cnt, base, posM, neg, N);
    hipLaunchKernelGGL(lossK, dim3(1), dim3(256), 0, stream, posM, neg, out, N);
  } else {
    hipLaunchKernelGGL(wsFailK, dim3(1), dim3(64), 0, stream, out);
  }
}